// Round 10
// baseline (357.753 us; speedup 1.0000x reference)
//
#include <hip/hip_runtime.h>
#include <hip/hip_bf16.h>

#define NN 50000
#define PADN 50048            // 782*64 — padded row count
#define EE 800000
#define HH 256
#define EPSBN 1e-5f
#define NBLK ((NN + 255) / 256)   // 196 scan blocks
#define CR_T 100096               // count_rank threads (391 blocks * 256), 8 edges each
#define FC_T 200192               // fill_csr threads (782 blocks * 256), 4 edges each

typedef unsigned int uint32;
typedef __attribute__((ext_vector_type(8))) short short8;   // 8 bf16 = 4 VGPR
typedef __attribute__((ext_vector_type(4))) float f32x4;
typedef __attribute__((ext_vector_type(2))) float f32x2;

__device__ __forceinline__ float bf2f(unsigned short u) {
    union { uint32 u; float f; } c; c.u = ((uint32)u) << 16; return c.f;
}
__device__ __forceinline__ unsigned short f2bf(float f) {
    __hip_bfloat16 h = __float2bfloat16(f);   // RNE
    return *reinterpret_cast<unsigned short*>(&h);
}
// pack 4 floats -> 4 fp8 e4m3 (OCP on gfx950), RNE+sat
__device__ __forceinline__ uint32 pkfp8(float a, float b, float c, float d) {
    int r = 0;
    r = __builtin_amdgcn_cvt_pk_fp8_f32(a, b, r, false);   // bytes 0,1
    r = __builtin_amdgcn_cvt_pk_fp8_f32(c, d, r, true);    // bytes 2,3
    return (uint32)r;
}

// ---------------- prologue ----------------

// bf16 + fp8 copies of x; also zeroes deg (first kernel in stream)
__global__ void cvt_x(const float* __restrict__ x, unsigned short* __restrict__ xb,
                      unsigned char* __restrict__ x8, int* __restrict__ deg) {
    int i = blockIdx.x * blockDim.x + threadIdx.x;
    if (i < NN) deg[i] = 0;
    if (i >= PADN * 128 / 8) return;
    const int e0 = i * 8;
    float f[8];
    if (e0 + 8 <= NN * 128) {
        float4 u0 = *(const float4*)(x + e0);
        float4 u1 = *(const float4*)(x + e0 + 4);
        f[0] = u0.x; f[1] = u0.y; f[2] = u0.z; f[3] = u0.w;
        f[4] = u1.x; f[5] = u1.y; f[6] = u1.z; f[7] = u1.w;
    } else {
        #pragma unroll
        for (int k = 0; k < 8; ++k) f[k] = 0.f;   // pad rows
    }
    uint4 b;
    b.x = (uint32)f2bf(f[0]) | ((uint32)f2bf(f[1]) << 16);
    b.y = (uint32)f2bf(f[2]) | ((uint32)f2bf(f[3]) << 16);
    b.z = (uint32)f2bf(f[4]) | ((uint32)f2bf(f[5]) << 16);
    b.w = (uint32)f2bf(f[6]) | ((uint32)f2bf(f[7]) << 16);
    *(uint4*)(xb + e0) = b;
    uint2 p;
    p.x = pkfp8(f[0], f[1], f[2], f[3]);
    p.y = pkfp8(f[4], f[5], f[6], f[7]);
    *(uint2*)(x8 + e0) = p;
}

// 8 edges/thread, batch-issued atomics (MLP over atomic latency)
__global__ void count_rank(const int* __restrict__ dst, int* __restrict__ deg,
                           int* __restrict__ rank) {
    const int t = (int)(blockIdx.x * blockDim.x + threadIdx.x);
    int d[8], r[8];
    #pragma unroll
    for (int k = 0; k < 8; ++k) {
        const int e = t + k * CR_T;
        d[k] = (e < EE) ? dst[e] : -1;
    }
    #pragma unroll
    for (int k = 0; k < 8; ++k)
        if (d[k] >= 0) r[k] = atomicAdd(&deg[d[k]], 1);
    #pragma unroll
    for (int k = 0; k < 8; ++k) {
        const int e = t + k * CR_T;
        if (d[k] >= 0) rank[e] = r[k];
    }
}

__global__ void scan_part(const int* __restrict__ deg, int* __restrict__ bsum) {
    __shared__ int sd[256];
    const int t = (int)threadIdx.x;
    const int i = (int)blockIdx.x * 256 + t;
    sd[t] = (i < NN) ? deg[i] : 0;
    __syncthreads();
    #pragma unroll
    for (int off = 128; off > 0; off >>= 1) {
        if (t < off) sd[t] += sd[t + off];
        __syncthreads();
    }
    if (t == 0) bsum[blockIdx.x] = sd[0];
}

// merged: each block re-reduces bsum[0..b-1] for its offset, then scans its chunk
__global__ void scan_fin(const int* __restrict__ deg, const int* __restrict__ bsum,
                         int* __restrict__ rowstart) {
    __shared__ int sb[256];
    __shared__ int sd[256];
    const int t = (int)threadIdx.x;
    const int b = (int)blockIdx.x;
    sb[t] = (t < NBLK && t < b) ? bsum[t] : 0;
    __syncthreads();
    #pragma unroll
    for (int off = 128; off > 0; off >>= 1) {
        if (t < off) sb[t] += sb[t + off];
        __syncthreads();
    }
    const int boff = sb[0];
    const int i = b * 256 + t;
    const int v = (i < NN) ? deg[i] : 0;
    sd[t] = v;
    __syncthreads();
    #pragma unroll
    for (int off = 1; off < 256; off <<= 1) {
        int u = (t >= off) ? sd[t - off] : 0;
        __syncthreads();
        sd[t] += u;
        __syncthreads();
    }
    if (i < NN) rowstart[i] = boff + sd[t] - v;
    if (i == 0) rowstart[NN] = EE;
}

// 4 edges/thread, batched dependent gather + scattered store
__global__ void fill_csr2(const int* __restrict__ src, const int* __restrict__ dst,
                          const int* __restrict__ rank, const int* __restrict__ rowstart,
                          int* __restrict__ col) {
    const int t = (int)(blockIdx.x * blockDim.x + threadIdx.x);
    int d[4], r[4], s[4], p[4];
    #pragma unroll
    for (int k = 0; k < 4; ++k) {
        const int e = t + k * FC_T;
        const bool ok = e < EE;
        d[k] = ok ? dst[e] : -1;
        r[k] = ok ? rank[e] : 0;
        s[k] = ok ? src[e] : 0;
    }
    #pragma unroll
    for (int k = 0; k < 4; ++k)
        if (d[k] >= 0) p[k] = rowstart[d[k]];
    #pragma unroll
    for (int k = 0; k < 4; ++k)
        if (d[k] >= 0) col[p[k] + r[k]] = s[k];
}

// Wpack layout (bf16 elems): idx = ((s*16 + nf)*512 + l*8 + e)
__device__ __forceinline__ void pack_one(const float* __restrict__ Wl,
                                         const float* __restrict__ Wr,
                                         unsigned short* __restrict__ Wp,
                                         int C, int idx) {
    int e  = idx & 7;
    int ll = (idx >> 3) & 63;
    int nf = (idx >> 9) & 15;
    int s  = idx >> 13;
    int KSl = C / 32;
    const float* W = (s < KSl) ? Wl : Wr;
    int ks = (s < KSl) ? s : s - KSl;
    int k = ks * 32 + (ll >> 4) * 8 + e;
    int n = nf * 16 + (ll & 15);
    Wp[idx] = f2bf(W[(size_t)k * HH + n]);
}

__global__ void pack_w3(const float* __restrict__ Wl0, const float* __restrict__ Wr0,
                        unsigned short* __restrict__ Wp0,
                        const float* __restrict__ Wl1, const float* __restrict__ Wr1,
                        unsigned short* __restrict__ Wp1,
                        const float* __restrict__ Wl2, const float* __restrict__ Wr2,
                        unsigned short* __restrict__ Wp2) {
    int idx = blockIdx.x * blockDim.x + threadIdx.x;
    if (idx < 65536)       pack_one(Wl0, Wr0, Wp0, 128, idx);
    else if (idx < 196608) pack_one(Wl1, Wr1, Wp1, 256, idx - 65536);
    else if (idx < 327680) pack_one(Wl2, Wr2, Wp2, 256, idx - 196608);
}

// ---------------- mean aggregation (fp8 gather -> bf16 out), one wave/node ----------------
// 16B/lane gathers, 4 rows in flight per sub-wave -> 16 rows in flight per wave.

__device__ __forceinline__ void acc16f(float* a, uint4 v) {
    f32x2 t;
    t = __builtin_amdgcn_cvt_pk_f32_fp8(v.x, false); a[0]  += t.x; a[1]  += t.y;
    t = __builtin_amdgcn_cvt_pk_f32_fp8(v.x, true);  a[2]  += t.x; a[3]  += t.y;
    t = __builtin_amdgcn_cvt_pk_f32_fp8(v.y, false); a[4]  += t.x; a[5]  += t.y;
    t = __builtin_amdgcn_cvt_pk_f32_fp8(v.y, true);  a[6]  += t.x; a[7]  += t.y;
    t = __builtin_amdgcn_cvt_pk_f32_fp8(v.z, false); a[8]  += t.x; a[9]  += t.y;
    t = __builtin_amdgcn_cvt_pk_f32_fp8(v.z, true);  a[10] += t.x; a[11] += t.y;
    t = __builtin_amdgcn_cvt_pk_f32_fp8(v.w, false); a[12] += t.x; a[13] += t.y;
    t = __builtin_amdgcn_cvt_pk_f32_fp8(v.w, true);  a[14] += t.x; a[15] += t.y;
}

template<int C>
__global__ void agg_mean_8(const unsigned char* __restrict__ h8, const int* __restrict__ rowstart,
                           const int* __restrict__ col,
                           unsigned short* __restrict__ agg) {
    const int wid = (int)((blockIdx.x * blockDim.x + threadIdx.x) >> 6);
    const int l   = (int)(threadIdx.x & 63);
    if (wid >= NN) return;
    const int beg = rowstart[wid], end = rowstart[wid + 1];
    const int d   = end - beg;
    const float inv = 1.0f / (float)(d > 1 ? d : 1);
    float a[16];
    #pragma unroll
    for (int k = 0; k < 16; ++k) a[k] = 0.f;

    // sub-wave geometry: C=256 -> 16 lanes/row (4 quarters); C=128 -> 8 lanes/row (8 octs)
    constexpr int LPR  = C / 16;          // lanes per row (16 or 8)
    constexpr int NSW  = 64 / LPR;        // sub-waves per wave (4 or 8)
    const int sw = l / LPR;               // sub-wave index
    const int cl = l % LPR;               // lane within row
    const unsigned char* base = h8 + cl * 16;

    int j = beg + sw;
    for (; j + 3 * NSW < end; j += 4 * NSW) {   // 4 independent rows per sub-wave
        int c0 = col[j], c1 = col[j + NSW], c2 = col[j + 2 * NSW], c3 = col[j + 3 * NSW];
        uint4 v0 = *(const uint4*)(base + (size_t)c0 * C);
        uint4 v1 = *(const uint4*)(base + (size_t)c1 * C);
        uint4 v2 = *(const uint4*)(base + (size_t)c2 * C);
        uint4 v3 = *(const uint4*)(base + (size_t)c3 * C);
        acc16f(a, v0); acc16f(a, v1); acc16f(a, v2); acc16f(a, v3);
    }
    for (; j < end; j += NSW) {
        uint4 v0 = *(const uint4*)(base + (size_t)col[j] * C);
        acc16f(a, v0);
    }
    // cross-sub-wave reduce
    if (C == 128) {
        #pragma unroll
        for (int k = 0; k < 16; ++k) a[k] += __shfl_xor(a[k], 8, 64);
    }
    #pragma unroll
    for (int k = 0; k < 16; ++k) {
        a[k] += __shfl_xor(a[k], 16, 64);
        a[k] += __shfl_xor(a[k], 32, 64);
    }
    if (sw == 0) {
        uint4 o0, o1;
        o0.x = (uint32)f2bf(a[0]  * inv) | ((uint32)f2bf(a[1]  * inv) << 16);
        o0.y = (uint32)f2bf(a[2]  * inv) | ((uint32)f2bf(a[3]  * inv) << 16);
        o0.z = (uint32)f2bf(a[4]  * inv) | ((uint32)f2bf(a[5]  * inv) << 16);
        o0.w = (uint32)f2bf(a[6]  * inv) | ((uint32)f2bf(a[7]  * inv) << 16);
        o1.x = (uint32)f2bf(a[8]  * inv) | ((uint32)f2bf(a[9]  * inv) << 16);
        o1.y = (uint32)f2bf(a[10] * inv) | ((uint32)f2bf(a[11] * inv) << 16);
        o1.z = (uint32)f2bf(a[12] * inv) | ((uint32)f2bf(a[13] * inv) << 16);
        o1.w = (uint32)f2bf(a[14] * inv) | ((uint32)f2bf(a[15] * inv) << 16);
        *(uint4*)(agg + (size_t)wid * C + cl * 16) = o0;
        *(uint4*)(agg + (size_t)wid * C + cl * 16 + 8) = o1;
    }
}

// ---------------- MFMA GEMM: out = relu(BN(agg@Wl + h@Wr + b)) ----------------
// 64 rows x 256 cols per block, 4 waves, K = 2*C fused, BK=64 staging.
// Output staged through LDS for fully-coalesced stores.

#define CPAD 260   // padded cols (f32 rows: stride 1040B; bf16 rows: 520B)

template<int C, bool FINAL>
__global__ __launch_bounds__(256)
void gemm_mfma(const unsigned short* __restrict__ Aagg, const unsigned short* __restrict__ Ain,
               const unsigned short* __restrict__ Wpack,
               const float* __restrict__ bias, const float* __restrict__ gamma,
               const float* __restrict__ beta, const float* __restrict__ rmean,
               const float* __restrict__ rvar,
               float* __restrict__ outf, unsigned short* __restrict__ outb,
               unsigned char* __restrict__ out8)
{
    constexpr int KS = C / 32;      // k-steps per matrix
    constexpr int S  = 2 * KS;      // total k-steps (agg@Wl then h@Wr)
    constexpr int NS = S / 2;       // stages (2 k-steps each)
    __shared__ unsigned short Alds[2][4][1024];      // dbuf x m-frag x (2 ksteps * 512)
    __shared__ __align__(16) unsigned char Cbuf[33280];  // f32 32xCPAD | bf16 64xCPAD
    const int tid = (int)threadIdx.x;
    const int wid = tid >> 6;       // wave -> 64-col slab
    const int l   = tid & 63;
    const int row0 = (int)blockIdx.x * 64;

    const int srow  = row0 + wid * 16 + (l & 15);
    const int skoff = (l >> 4) * 8;

    f32x4 acc[4][4];
    #pragma unroll
    for (int m = 0; m < 4; ++m)
        #pragma unroll
        for (int n = 0; n < 4; ++n)
            acc[m][n] = (f32x4){0.f, 0.f, 0.f, 0.f};

    auto stage = [&](int buf, int st) {
        #pragma unroll
        for (int k2 = 0; k2 < 2; ++k2) {
            const int s = st * 2 + k2;
            const unsigned short* Asrc = (s < KS) ? Aagg : Ain;
            const int ks = (s < KS) ? s : s - KS;
            const unsigned short* gp = Asrc + (size_t)srow * C + ks * 32 + skoff;
            __builtin_amdgcn_global_load_lds(
                (const __attribute__((address_space(1))) uint32*)gp,
                (__attribute__((address_space(3))) uint32*)(&Alds[buf][wid][k2 * 512]),
                16, 0, 0);
        }
    };

    stage(0, 0);
    int cur = 0;
    for (int st = 0; st < NS; ++st) {
        __syncthreads();                        // Alds[cur] staged (vmcnt drained)
        if (st + 1 < NS) stage(cur ^ 1, st + 1);
        short8 b[2][4];
        #pragma unroll
        for (int k2 = 0; k2 < 2; ++k2)
            #pragma unroll
            for (int n = 0; n < 4; ++n) {
                size_t off = ((size_t)(st * 2 + k2) * 16 + wid * 4 + n) * 512 + l * 8;
                b[k2][n] = *(const short8*)(Wpack + off);
            }
        short8 a[2][4];
        #pragma unroll
        for (int k2 = 0; k2 < 2; ++k2)
            #pragma unroll
            for (int m = 0; m < 4; ++m)
                a[k2][m] = *(const short8*)(&Alds[cur][m][k2 * 512 + l * 8]);
        #pragma unroll
        for (int k2 = 0; k2 < 2; ++k2)
            #pragma unroll
            for (int m = 0; m < 4; ++m)
                #pragma unroll
                for (int n = 0; n < 4; ++n)
                    acc[m][n] = __builtin_amdgcn_mfma_f32_16x16x32_bf16(a[k2][m], b[k2][n], acc[m][n], 0, 0, 0);
        cur ^= 1;
    }

    // BN constants per output column (4 n-frags)
    float sj[4], cj[4];
    #pragma unroll
    for (int n = 0; n < 4; ++n) {
        const int jj = wid * 64 + n * 16 + (l & 15);
        sj[n] = gamma[jj] * rsqrtf(rvar[jj] + EPSBN);
        cj[n] = (bias[jj] - rmean[jj]) * sj[n] + beta[jj];
    }

    if (FINAL) {
        // two half-passes: rows 0-31 (m=0,1) then 32-63 (m=2,3), f32 through LDS
        float* Cf = (float*)Cbuf;
        #pragma unroll
        for (int half = 0; half < 2; ++half) {
            if (half) __syncthreads();          // protect Cf reuse
            #pragma unroll
            for (int n = 0; n < 4; ++n) {
                const int jj = wid * 64 + n * 16 + (l & 15);
                #pragma unroll
                for (int mm = 0; mm < 2; ++mm) {
                    const int m  = half * 2 + mm;
                    const int rb = mm * 16 + (l >> 4) * 4;   // 0..31 within half
                    #pragma unroll
                    for (int j = 0; j < 4; ++j) {
                        float v = acc[m][n][j] * sj[n] + cj[n];
                        Cf[(rb + j) * CPAD + jj] = v > 0.f ? v : 0.f;
                    }
                }
            }
            __syncthreads();
            const int col4 = (tid & 63) * 4;
            const int rw   = tid >> 6;
            #pragma unroll
            for (int i = 0; i < 8; ++i) {
                const int row  = i * 4 + rw;
                const int grow = row0 + half * 32 + row;
                if (grow < NN) {
                    float4 v = *(const float4*)&Cf[row * CPAD + col4];
                    *(float4*)(outf + (size_t)grow * HH + col4) = v;
                }
            }
        }
    } else {
        unsigned short* Clds = (unsigned short*)Cbuf;
        #pragma unroll
        for (int n = 0; n < 4; ++n) {
            const int jj = wid * 64 + n * 16 + (l & 15);
            #pragma unroll
            for (int m = 0; m < 4; ++m) {
                const int rb = m * 16 + (l >> 4) * 4;
                #pragma unroll
                for (int j = 0; j < 4; ++j) {
                    float v = acc[m][n][j] * sj[n] + cj[n];
                    Clds[(rb + j) * CPAD + jj] = f2bf(v > 0.f ? v : 0.f);
                }
            }
        }
        __syncthreads();
        // linear write-out: bf16 (16B/thread x8) + fp8 gather copy (8B/thread x8)
        #pragma unroll
        for (int i = 0; i < 8; ++i) {
            const int row  = i * 8 + (tid >> 5);
            const int col8 = (tid & 31) * 8;
            uint4 v = *(const uint4*)&Clds[row * CPAD + col8];
            *(uint4*)(outb + ((size_t)(row0 + row)) * HH + col8) = v;
            uint2 p;
            p.x = pkfp8(bf2f((unsigned short)(v.x & 0xffff)), bf2f((unsigned short)(v.x >> 16)),
                        bf2f((unsigned short)(v.y & 0xffff)), bf2f((unsigned short)(v.y >> 16)));
            p.y = pkfp8(bf2f((unsigned short)(v.z & 0xffff)), bf2f((unsigned short)(v.z >> 16)),
                        bf2f((unsigned short)(v.w & 0xffff)), bf2f((unsigned short)(v.w >> 16)));
            *(uint2*)(out8 + ((size_t)(row0 + row)) * HH + col8) = p;
        }
    }
}

// ---------------- launch ----------------

static inline size_t alignup(size_t x) { return (x + 511) & ~(size_t)511; }

extern "C" void kernel_launch(void* const* d_in, const int* in_sizes, int n_in,
                              void* d_out, int out_size, void* d_ws, size_t ws_size,
                              hipStream_t stream) {
    const float* x   = (const float*)d_in[0];
    const int*   ei  = (const int*)d_in[1];
    const int*   src = ei;
    const int*   dst = ei + EE;
    const float* gamma = (const float*)d_in[2];
    const float* beta  = (const float*)d_in[3];
    const float* rmean = (const float*)d_in[4];
    const float* rvar  = (const float*)d_in[5];
    const float* Wl0 = (const float*)d_in[6];
    const float* Wr0 = (const float*)d_in[7];
    const float* b0  = (const float*)d_in[8];
    const float* Wl1 = (const float*)d_in[9];
    const float* Wr1 = (const float*)d_in[10];
    const float* b1  = (const float*)d_in[11];
    const float* Wl2 = (const float*)d_in[12];
    const float* Wr2 = (const float*)d_in[13];
    const float* b2  = (const float*)d_in[14];
    float* out = (float*)d_out;
    (void)ws_size; (void)n_in; (void)in_sizes; (void)out_size;

    char* w = (char*)d_ws;
    size_t off = 0;
    int*   deg      = (int*)(w + off);   off += alignup(NN * 4);
    int*   rank     = (int*)(w + off);   off += alignup((size_t)EE * 4);
    int*   rowstart = (int*)(w + off);   off += alignup((NN + 1) * 4);
    int*   bsum     = (int*)(w + off);   off += alignup(NBLK * 4);
    int*   col      = (int*)(w + off);   off += alignup((size_t)EE * 4);
    unsigned short* xb   = (unsigned short*)(w + off); off += alignup((size_t)PADN * 128 * 2);
    unsigned short* agg  = (unsigned short*)(w + off); off += alignup((size_t)PADN * HH * 2);
    unsigned short* h1   = (unsigned short*)(w + off); off += alignup((size_t)PADN * HH * 2);
    unsigned short* h2   = (unsigned short*)(w + off); off += alignup((size_t)PADN * HH * 2);
    unsigned char*  x8   = (unsigned char*)(w + off);  off += alignup((size_t)PADN * 128);
    unsigned char*  h1_8 = (unsigned char*)(w + off);  off += alignup((size_t)PADN * HH);
    unsigned char*  h2_8 = (unsigned char*)(w + off);  off += alignup((size_t)PADN * HH);
    unsigned short* Wp0  = (unsigned short*)(w + off); off += alignup((size_t)2 * 128 * 256 * 2);
    unsigned short* Wp1  = (unsigned short*)(w + off); off += alignup((size_t)2 * 256 * 256 * 2);
    unsigned short* Wp2  = (unsigned short*)(w + off); off += alignup((size_t)2 * 256 * 256 * 2);

    // prologue (6 dispatches): conversions + CSR build
    cvt_x     <<<(PADN * 128 / 8 + 255) / 256, 256, 0, stream>>>(x, xb, x8, deg);
    count_rank<<<CR_T / 256, 256, 0, stream>>>(dst, deg, rank);
    scan_part <<<NBLK, 256, 0, stream>>>(deg, bsum);
    scan_fin  <<<NBLK, 256, 0, stream>>>(deg, bsum, rowstart);
    fill_csr2 <<<FC_T / 256, 256, 0, stream>>>(src, dst, rank, rowstart, col);
    pack_w3   <<<1280, 256, 0, stream>>>(Wl0, Wr0, Wp0, Wl1, Wr1, Wp1, Wl2, Wr2, Wp2);

    const int agg_grid  = (NN * 64 + 255) / 256;
    const int gemm_grid = PADN / 64;   // 782

    // layer 0 (C=128)
    agg_mean_8<128><<<agg_grid, 256, 0, stream>>>(x8, rowstart, col, agg);
    gemm_mfma<128, false><<<gemm_grid, 256, 0, stream>>>(agg, xb, Wp0,
        b0, gamma + 0 * HH, beta + 0 * HH, rmean + 0 * HH, rvar + 0 * HH, nullptr, h1, h1_8);

    // layer 1 (C=256)
    agg_mean_8<256><<<agg_grid, 256, 0, stream>>>(h1_8, rowstart, col, agg);
    gemm_mfma<256, false><<<gemm_grid, 256, 0, stream>>>(agg, h1, Wp1,
        b1, gamma + 1 * HH, beta + 1 * HH, rmean + 1 * HH, rvar + 1 * HH, nullptr, h2, h2_8);

    // layer 2 (C=256)
    agg_mean_8<256><<<agg_grid, 256, 0, stream>>>(h2_8, rowstart, col, agg);
    gemm_mfma<256, true><<<gemm_grid, 256, 0, stream>>>(agg, h2, Wp2,
        b2, gamma + 2 * HH, beta + 2 * HH, rmean + 2 * HH, rvar + 2 * HH, out, nullptr, nullptr);
}

// Round 11
// 330.864 us; speedup vs baseline: 1.0813x; 1.0813x over previous
//
#include <hip/hip_runtime.h>
#include <hip/hip_bf16.h>

#define NN 50000
#define PADN 50048            // 782*64 — padded row count
#define EE 800000
#define HH 256
#define EPSBN 1e-5f
#define NBLK ((NN + 255) / 256)   // 196 scan blocks
#define CR_T 100096               // count_rank threads (391 blocks * 256), 8 edges each
#define FC_T 200192               // fill_csr threads (782 blocks * 256), 4 edges each

typedef unsigned int uint32;
typedef __attribute__((ext_vector_type(8))) short short8;   // 8 bf16 = 4 VGPR
typedef __attribute__((ext_vector_type(4))) float f32x4;
typedef __attribute__((ext_vector_type(2))) float f32x2;

__device__ __forceinline__ float bf2f(unsigned short u) {
    union { uint32 u; float f; } c; c.u = ((uint32)u) << 16; return c.f;
}
__device__ __forceinline__ unsigned short f2bf(float f) {
    __hip_bfloat16 h = __float2bfloat16(f);   // RNE
    return *reinterpret_cast<unsigned short*>(&h);
}
// pack 4 floats -> 4 fp8 e4m3 (OCP on gfx950), RNE+sat
__device__ __forceinline__ uint32 pkfp8(float a, float b, float c, float d) {
    int r = 0;
    r = __builtin_amdgcn_cvt_pk_fp8_f32(a, b, r, false);   // bytes 0,1
    r = __builtin_amdgcn_cvt_pk_fp8_f32(c, d, r, true);    // bytes 2,3
    return (uint32)r;
}

// ---------------- prologue ----------------

// bf16 + fp8 copies of x; also zeroes deg (first kernel in stream)
__global__ void cvt_x(const float* __restrict__ x, unsigned short* __restrict__ xb,
                      unsigned char* __restrict__ x8, int* __restrict__ deg) {
    int i = blockIdx.x * blockDim.x + threadIdx.x;
    if (i < NN) deg[i] = 0;
    if (i >= PADN * 128 / 8) return;
    const int e0 = i * 8;
    float f[8];
    if (e0 + 8 <= NN * 128) {
        float4 u0 = *(const float4*)(x + e0);
        float4 u1 = *(const float4*)(x + e0 + 4);
        f[0] = u0.x; f[1] = u0.y; f[2] = u0.z; f[3] = u0.w;
        f[4] = u1.x; f[5] = u1.y; f[6] = u1.z; f[7] = u1.w;
    } else {
        #pragma unroll
        for (int k = 0; k < 8; ++k) f[k] = 0.f;   // pad rows
    }
    uint4 b;
    b.x = (uint32)f2bf(f[0]) | ((uint32)f2bf(f[1]) << 16);
    b.y = (uint32)f2bf(f[2]) | ((uint32)f2bf(f[3]) << 16);
    b.z = (uint32)f2bf(f[4]) | ((uint32)f2bf(f[5]) << 16);
    b.w = (uint32)f2bf(f[6]) | ((uint32)f2bf(f[7]) << 16);
    *(uint4*)(xb + e0) = b;
    uint2 p;
    p.x = pkfp8(f[0], f[1], f[2], f[3]);
    p.y = pkfp8(f[4], f[5], f[6], f[7]);
    *(uint2*)(x8 + e0) = p;
}

// 8 edges/thread, batch-issued atomics (MLP over atomic latency)
__global__ void count_rank(const int* __restrict__ dst, int* __restrict__ deg,
                           int* __restrict__ rank) {
    const int t = (int)(blockIdx.x * blockDim.x + threadIdx.x);
    int d[8], r[8];
    #pragma unroll
    for (int k = 0; k < 8; ++k) {
        const int e = t + k * CR_T;
        d[k] = (e < EE) ? dst[e] : -1;
    }
    #pragma unroll
    for (int k = 0; k < 8; ++k)
        if (d[k] >= 0) r[k] = atomicAdd(&deg[d[k]], 1);
    #pragma unroll
    for (int k = 0; k < 8; ++k) {
        const int e = t + k * CR_T;
        if (d[k] >= 0) rank[e] = r[k];
    }
}

__global__ void scan_part(const int* __restrict__ deg, int* __restrict__ bsum) {
    __shared__ int sd[256];
    const int t = (int)threadIdx.x;
    const int i = (int)blockIdx.x * 256 + t;
    sd[t] = (i < NN) ? deg[i] : 0;
    __syncthreads();
    #pragma unroll
    for (int off = 128; off > 0; off >>= 1) {
        if (t < off) sd[t] += sd[t + off];
        __syncthreads();
    }
    if (t == 0) bsum[blockIdx.x] = sd[0];
}

// merged: each block re-reduces bsum[0..b-1] for its offset, then scans its chunk
__global__ void scan_fin(const int* __restrict__ deg, const int* __restrict__ bsum,
                         int* __restrict__ rowstart) {
    __shared__ int sb[256];
    __shared__ int sd[256];
    const int t = (int)threadIdx.x;
    const int b = (int)blockIdx.x;
    sb[t] = (t < NBLK && t < b) ? bsum[t] : 0;
    __syncthreads();
    #pragma unroll
    for (int off = 128; off > 0; off >>= 1) {
        if (t < off) sb[t] += sb[t + off];
        __syncthreads();
    }
    const int boff = sb[0];
    const int i = b * 256 + t;
    const int v = (i < NN) ? deg[i] : 0;
    sd[t] = v;
    __syncthreads();
    #pragma unroll
    for (int off = 1; off < 256; off <<= 1) {
        int u = (t >= off) ? sd[t - off] : 0;
        __syncthreads();
        sd[t] += u;
        __syncthreads();
    }
    if (i < NN) rowstart[i] = boff + sd[t] - v;
    if (i == 0) rowstart[NN] = EE;
}

// 4 edges/thread, batched dependent gather + scattered store
__global__ void fill_csr2(const int* __restrict__ src, const int* __restrict__ dst,
                          const int* __restrict__ rank, const int* __restrict__ rowstart,
                          int* __restrict__ col) {
    const int t = (int)(blockIdx.x * blockDim.x + threadIdx.x);
    int d[4], r[4], s[4], p[4];
    #pragma unroll
    for (int k = 0; k < 4; ++k) {
        const int e = t + k * FC_T;
        const bool ok = e < EE;
        d[k] = ok ? dst[e] : -1;
        r[k] = ok ? rank[e] : 0;
        s[k] = ok ? src[e] : 0;
    }
    #pragma unroll
    for (int k = 0; k < 4; ++k)
        if (d[k] >= 0) p[k] = rowstart[d[k]];
    #pragma unroll
    for (int k = 0; k < 4; ++k)
        if (d[k] >= 0) col[p[k] + r[k]] = s[k];
}

// Wpack layout (bf16 elems): idx = ((s*16 + nf)*512 + l*8 + e)
__device__ __forceinline__ void pack_one(const float* __restrict__ Wl,
                                         const float* __restrict__ Wr,
                                         unsigned short* __restrict__ Wp,
                                         int C, int idx) {
    int e  = idx & 7;
    int ll = (idx >> 3) & 63;
    int nf = (idx >> 9) & 15;
    int s  = idx >> 13;
    int KSl = C / 32;
    const float* W = (s < KSl) ? Wl : Wr;
    int ks = (s < KSl) ? s : s - KSl;
    int k = ks * 32 + (ll >> 4) * 8 + e;
    int n = nf * 16 + (ll & 15);
    Wp[idx] = f2bf(W[(size_t)k * HH + n]);
}

__global__ void pack_w3(const float* __restrict__ Wl0, const float* __restrict__ Wr0,
                        unsigned short* __restrict__ Wp0,
                        const float* __restrict__ Wl1, const float* __restrict__ Wr1,
                        unsigned short* __restrict__ Wp1,
                        const float* __restrict__ Wl2, const float* __restrict__ Wr2,
                        unsigned short* __restrict__ Wp2) {
    int idx = blockIdx.x * blockDim.x + threadIdx.x;
    if (idx < 65536)       pack_one(Wl0, Wr0, Wp0, 128, idx);
    else if (idx < 196608) pack_one(Wl1, Wr1, Wp1, 256, idx - 65536);
    else if (idx < 327680) pack_one(Wl2, Wr2, Wp2, 256, idx - 196608);
}

// ---------------- mean aggregation (fp8 gather -> bf16 out), one wave/node ----------------
// R9 config (best measured): 8B/lane gathers, 4 rows in flight, 28 VGPR, no LDS
// -> ~21 waves/CU. Rows-in-flight/CU ≈ waves x 4 beats per-lane depth (R10 lesson).

__device__ __forceinline__ void acc8f(float* a, uint2 v) {
    f32x2 f0 = __builtin_amdgcn_cvt_pk_f32_fp8(v.x, false);
    f32x2 f1 = __builtin_amdgcn_cvt_pk_f32_fp8(v.x, true);
    f32x2 f2 = __builtin_amdgcn_cvt_pk_f32_fp8(v.y, false);
    f32x2 f3 = __builtin_amdgcn_cvt_pk_f32_fp8(v.y, true);
    a[0] += f0.x; a[1] += f0.y; a[2] += f1.x; a[3] += f1.y;
    a[4] += f2.x; a[5] += f2.y; a[6] += f3.x; a[7] += f3.y;
}

template<int C>
__global__ void agg_mean_8(const unsigned char* __restrict__ h8, const int* __restrict__ rowstart,
                           const int* __restrict__ col,
                           unsigned short* __restrict__ agg) {
    const int wid = (int)((blockIdx.x * blockDim.x + threadIdx.x) >> 6);
    const int l   = (int)(threadIdx.x & 63);
    if (wid >= NN) return;
    const int beg = rowstart[wid], end = rowstart[wid + 1];
    const int d   = end - beg;
    const float inv = 1.0f / (float)(d > 1 ? d : 1);
    float a[8] = {0.f, 0.f, 0.f, 0.f, 0.f, 0.f, 0.f, 0.f};

    if (C == 256) {
        const int half = l >> 5;
        const int cl   = l & 31;
        const unsigned char* base = h8 + cl * 8;
        int j = beg + half;
        for (; j + 6 < end; j += 8) {
            int c0 = col[j], c1 = col[j + 2], c2 = col[j + 4], c3 = col[j + 6];
            uint2 v0 = *(const uint2*)(base + (size_t)c0 * C);
            uint2 v1 = *(const uint2*)(base + (size_t)c1 * C);
            uint2 v2 = *(const uint2*)(base + (size_t)c2 * C);
            uint2 v3 = *(const uint2*)(base + (size_t)c3 * C);
            acc8f(a, v0); acc8f(a, v1); acc8f(a, v2); acc8f(a, v3);
        }
        for (; j < end; j += 2) {
            uint2 v0 = *(const uint2*)(base + (size_t)col[j] * C);
            acc8f(a, v0);
        }
        #pragma unroll
        for (int k = 0; k < 8; ++k) a[k] += __shfl_xor(a[k], 32, 64);
        if (half == 0) {
            uint4 o;
            o.x = (uint32)f2bf(a[0] * inv) | ((uint32)f2bf(a[1] * inv) << 16);
            o.y = (uint32)f2bf(a[2] * inv) | ((uint32)f2bf(a[3] * inv) << 16);
            o.z = (uint32)f2bf(a[4] * inv) | ((uint32)f2bf(a[5] * inv) << 16);
            o.w = (uint32)f2bf(a[6] * inv) | ((uint32)f2bf(a[7] * inv) << 16);
            *(uint4*)(agg + (size_t)wid * C + cl * 8) = o;
        }
    } else {  // C == 128
        const int q  = l >> 4;
        const int cl = l & 15;
        const unsigned char* base = h8 + cl * 8;
        int j = beg + q;
        for (; j + 12 < end; j += 16) {
            int c0 = col[j], c1 = col[j + 4], c2 = col[j + 8], c3 = col[j + 12];
            uint2 v0 = *(const uint2*)(base + (size_t)c0 * C);
            uint2 v1 = *(const uint2*)(base + (size_t)c1 * C);
            uint2 v2 = *(const uint2*)(base + (size_t)c2 * C);
            uint2 v3 = *(const uint2*)(base + (size_t)c3 * C);
            acc8f(a, v0); acc8f(a, v1); acc8f(a, v2); acc8f(a, v3);
        }
        for (; j < end; j += 4) {
            uint2 v0 = *(const uint2*)(base + (size_t)col[j] * C);
            acc8f(a, v0);
        }
        #pragma unroll
        for (int k = 0; k < 8; ++k) {
            a[k] += __shfl_xor(a[k], 16, 64);
            a[k] += __shfl_xor(a[k], 32, 64);
        }
        if (q == 0) {
            uint4 o;
            o.x = (uint32)f2bf(a[0] * inv) | ((uint32)f2bf(a[1] * inv) << 16);
            o.y = (uint32)f2bf(a[2] * inv) | ((uint32)f2bf(a[3] * inv) << 16);
            o.z = (uint32)f2bf(a[4] * inv) | ((uint32)f2bf(a[5] * inv) << 16);
            o.w = (uint32)f2bf(a[6] * inv) | ((uint32)f2bf(a[7] * inv) << 16);
            *(uint4*)(agg + (size_t)wid * C + cl * 8) = o;
        }
    }
}

// ---------------- MFMA GEMM: out = relu(BN(agg@Wl + h@Wr + b)) ----------------
// 64 rows x 256 cols per block, 4 waves, K = 2*C fused, BK=64 staging.
// Output staged through LDS for fully-coalesced stores.

#define CPAD 260   // padded cols (f32 rows: stride 1040B; bf16 rows: 520B)

template<int C, bool FINAL>
__global__ __launch_bounds__(256)
void gemm_mfma(const unsigned short* __restrict__ Aagg, const unsigned short* __restrict__ Ain,
               const unsigned short* __restrict__ Wpack,
               const float* __restrict__ bias, const float* __restrict__ gamma,
               const float* __restrict__ beta, const float* __restrict__ rmean,
               const float* __restrict__ rvar,
               float* __restrict__ outf, unsigned short* __restrict__ outb,
               unsigned char* __restrict__ out8)
{
    constexpr int KS = C / 32;      // k-steps per matrix
    constexpr int S  = 2 * KS;      // total k-steps (agg@Wl then h@Wr)
    constexpr int NS = S / 2;       // stages (2 k-steps each)
    __shared__ unsigned short Alds[2][4][1024];      // dbuf x m-frag x (2 ksteps * 512)
    __shared__ __align__(16) unsigned char Cbuf[33280];  // f32 32xCPAD | bf16 64xCPAD
    const int tid = (int)threadIdx.x;
    const int wid = tid >> 6;       // wave -> 64-col slab
    const int l   = tid & 63;
    const int row0 = (int)blockIdx.x * 64;

    const int srow  = row0 + wid * 16 + (l & 15);
    const int skoff = (l >> 4) * 8;

    f32x4 acc[4][4];
    #pragma unroll
    for (int m = 0; m < 4; ++m)
        #pragma unroll
        for (int n = 0; n < 4; ++n)
            acc[m][n] = (f32x4){0.f, 0.f, 0.f, 0.f};

    auto stage = [&](int buf, int st) {
        #pragma unroll
        for (int k2 = 0; k2 < 2; ++k2) {
            const int s = st * 2 + k2;
            const unsigned short* Asrc = (s < KS) ? Aagg : Ain;
            const int ks = (s < KS) ? s : s - KS;
            const unsigned short* gp = Asrc + (size_t)srow * C + ks * 32 + skoff;
            __builtin_amdgcn_global_load_lds(
                (const __attribute__((address_space(1))) uint32*)gp,
                (__attribute__((address_space(3))) uint32*)(&Alds[buf][wid][k2 * 512]),
                16, 0, 0);
        }
    };

    stage(0, 0);
    int cur = 0;
    for (int st = 0; st < NS; ++st) {
        __syncthreads();                        // Alds[cur] staged (vmcnt drained)
        if (st + 1 < NS) stage(cur ^ 1, st + 1);
        short8 b[2][4];
        #pragma unroll
        for (int k2 = 0; k2 < 2; ++k2)
            #pragma unroll
            for (int n = 0; n < 4; ++n) {
                size_t off = ((size_t)(st * 2 + k2) * 16 + wid * 4 + n) * 512 + l * 8;
                b[k2][n] = *(const short8*)(Wpack + off);
            }
        short8 a[2][4];
        #pragma unroll
        for (int k2 = 0; k2 < 2; ++k2)
            #pragma unroll
            for (int m = 0; m < 4; ++m)
                a[k2][m] = *(const short8*)(&Alds[cur][m][k2 * 512 + l * 8]);
        #pragma unroll
        for (int k2 = 0; k2 < 2; ++k2)
            #pragma unroll
            for (int m = 0; m < 4; ++m)
                #pragma unroll
                for (int n = 0; n < 4; ++n)
                    acc[m][n] = __builtin_amdgcn_mfma_f32_16x16x32_bf16(a[k2][m], b[k2][n], acc[m][n], 0, 0, 0);
        cur ^= 1;
    }

    // BN constants per output column (4 n-frags)
    float sj[4], cj[4];
    #pragma unroll
    for (int n = 0; n < 4; ++n) {
        const int jj = wid * 64 + n * 16 + (l & 15);
        sj[n] = gamma[jj] * rsqrtf(rvar[jj] + EPSBN);
        cj[n] = (bias[jj] - rmean[jj]) * sj[n] + beta[jj];
    }

    if (FINAL) {
        // two half-passes: rows 0-31 (m=0,1) then 32-63 (m=2,3), f32 through LDS
        float* Cf = (float*)Cbuf;
        #pragma unroll
        for (int half = 0; half < 2; ++half) {
            if (half) __syncthreads();          // protect Cf reuse
            #pragma unroll
            for (int n = 0; n < 4; ++n) {
                const int jj = wid * 64 + n * 16 + (l & 15);
                #pragma unroll
                for (int mm = 0; mm < 2; ++mm) {
                    const int m  = half * 2 + mm;
                    const int rb = mm * 16 + (l >> 4) * 4;   // 0..31 within half
                    #pragma unroll
                    for (int j = 0; j < 4; ++j) {
                        float v = acc[m][n][j] * sj[n] + cj[n];
                        Cf[(rb + j) * CPAD + jj] = v > 0.f ? v : 0.f;
                    }
                }
            }
            __syncthreads();
            const int col4 = (tid & 63) * 4;
            const int rw   = tid >> 6;
            #pragma unroll
            for (int i = 0; i < 8; ++i) {
                const int row  = i * 4 + rw;
                const int grow = row0 + half * 32 + row;
                if (grow < NN) {
                    float4 v = *(const float4*)&Cf[row * CPAD + col4];
                    *(float4*)(outf + (size_t)grow * HH + col4) = v;
                }
            }
        }
    } else {
        unsigned short* Clds = (unsigned short*)Cbuf;
        #pragma unroll
        for (int n = 0; n < 4; ++n) {
            const int jj = wid * 64 + n * 16 + (l & 15);
            #pragma unroll
            for (int m = 0; m < 4; ++m) {
                const int rb = m * 16 + (l >> 4) * 4;
                #pragma unroll
                for (int j = 0; j < 4; ++j) {
                    float v = acc[m][n][j] * sj[n] + cj[n];
                    Clds[(rb + j) * CPAD + jj] = f2bf(v > 0.f ? v : 0.f);
                }
            }
        }
        __syncthreads();
        // linear write-out: bf16 (16B/thread x8) + fp8 gather copy (8B/thread x8)
        #pragma unroll
        for (int i = 0; i < 8; ++i) {
            const int row  = i * 8 + (tid >> 5);
            const int col8 = (tid & 31) * 8;
            uint4 v = *(const uint4*)&Clds[row * CPAD + col8];
            *(uint4*)(outb + ((size_t)(row0 + row)) * HH + col8) = v;
            uint2 p;
            p.x = pkfp8(bf2f((unsigned short)(v.x & 0xffff)), bf2f((unsigned short)(v.x >> 16)),
                        bf2f((unsigned short)(v.y & 0xffff)), bf2f((unsigned short)(v.y >> 16)));
            p.y = pkfp8(bf2f((unsigned short)(v.z & 0xffff)), bf2f((unsigned short)(v.z >> 16)),
                        bf2f((unsigned short)(v.w & 0xffff)), bf2f((unsigned short)(v.w >> 16)));
            *(uint2*)(out8 + ((size_t)(row0 + row)) * HH + col8) = p;
        }
    }
}

// ---------------- launch ----------------

static inline size_t alignup(size_t x) { return (x + 511) & ~(size_t)511; }

extern "C" void kernel_launch(void* const* d_in, const int* in_sizes, int n_in,
                              void* d_out, int out_size, void* d_ws, size_t ws_size,
                              hipStream_t stream) {
    const float* x   = (const float*)d_in[0];
    const int*   ei  = (const int*)d_in[1];
    const int*   src = ei;
    const int*   dst = ei + EE;
    const float* gamma = (const float*)d_in[2];
    const float* beta  = (const float*)d_in[3];
    const float* rmean = (const float*)d_in[4];
    const float* rvar  = (const float*)d_in[5];
    const float* Wl0 = (const float*)d_in[6];
    const float* Wr0 = (const float*)d_in[7];
    const float* b0  = (const float*)d_in[8];
    const float* Wl1 = (const float*)d_in[9];
    const float* Wr1 = (const float*)d_in[10];
    const float* b1  = (const float*)d_in[11];
    const float* Wl2 = (const float*)d_in[12];
    const float* Wr2 = (const float*)d_in[13];
    const float* b2  = (const float*)d_in[14];
    float* out = (float*)d_out;
    (void)ws_size; (void)n_in; (void)in_sizes; (void)out_size;

    char* w = (char*)d_ws;
    size_t off = 0;
    int*   deg      = (int*)(w + off);   off += alignup(NN * 4);
    int*   rank     = (int*)(w + off);   off += alignup((size_t)EE * 4);
    int*   rowstart = (int*)(w + off);   off += alignup((NN + 1) * 4);
    int*   bsum     = (int*)(w + off);   off += alignup(NBLK * 4);
    int*   col      = (int*)(w + off);   off += alignup((size_t)EE * 4);
    unsigned short* xb   = (unsigned short*)(w + off); off += alignup((size_t)PADN * 128 * 2);
    unsigned short* agg  = (unsigned short*)(w + off); off += alignup((size_t)PADN * HH * 2);
    unsigned short* h1   = (unsigned short*)(w + off); off += alignup((size_t)PADN * HH * 2);
    unsigned short* h2   = (unsigned short*)(w + off); off += alignup((size_t)PADN * HH * 2);
    unsigned char*  x8   = (unsigned char*)(w + off);  off += alignup((size_t)PADN * 128);
    unsigned char*  h1_8 = (unsigned char*)(w + off);  off += alignup((size_t)PADN * HH);
    unsigned char*  h2_8 = (unsigned char*)(w + off);  off += alignup((size_t)PADN * HH);
    unsigned short* Wp0  = (unsigned short*)(w + off); off += alignup((size_t)2 * 128 * 256 * 2);
    unsigned short* Wp1  = (unsigned short*)(w + off); off += alignup((size_t)2 * 256 * 256 * 2);
    unsigned short* Wp2  = (unsigned short*)(w + off); off += alignup((size_t)2 * 256 * 256 * 2);

    // prologue (6 dispatches): conversions + CSR build
    cvt_x     <<<(PADN * 128 / 8 + 255) / 256, 256, 0, stream>>>(x, xb, x8, deg);
    count_rank<<<CR_T / 256, 256, 0, stream>>>(dst, deg, rank);
    scan_part <<<NBLK, 256, 0, stream>>>(deg, bsum);
    scan_fin  <<<NBLK, 256, 0, stream>>>(deg, bsum, rowstart);
    fill_csr2 <<<FC_T / 256, 256, 0, stream>>>(src, dst, rank, rowstart, col);
    pack_w3   <<<1280, 256, 0, stream>>>(Wl0, Wr0, Wp0, Wl1, Wr1, Wp1, Wl2, Wr2, Wp2);

    const int agg_grid  = (NN * 64 + 255) / 256;
    const int gemm_grid = PADN / 64;   // 782

    // layer 0 (C=128)
    agg_mean_8<128><<<agg_grid, 256, 0, stream>>>(x8, rowstart, col, agg);
    gemm_mfma<128, false><<<gemm_grid, 256, 0, stream>>>(agg, xb, Wp0,
        b0, gamma + 0 * HH, beta + 0 * HH, rmean + 0 * HH, rvar + 0 * HH, nullptr, h1, h1_8);

    // layer 1 (C=256)
    agg_mean_8<256><<<agg_grid, 256, 0, stream>>>(h1_8, rowstart, col, agg);
    gemm_mfma<256, false><<<gemm_grid, 256, 0, stream>>>(agg, h1, Wp1,
        b1, gamma + 1 * HH, beta + 1 * HH, rmean + 1 * HH, rvar + 1 * HH, nullptr, h2, h2_8);

    // layer 2 (C=256)
    agg_mean_8<256><<<agg_grid, 256, 0, stream>>>(h2_8, rowstart, col, agg);
    gemm_mfma<256, true><<<gemm_grid, 256, 0, stream>>>(agg, h2, Wp2,
        b2, gamma + 2 * HH, beta + 2 * HH, rmean + 2 * HH, rvar + 2 * HH, out, nullptr, nullptr);
}

// Round 12
// 330.171 us; speedup vs baseline: 1.0835x; 1.0021x over previous
//
#include <hip/hip_runtime.h>
#include <hip/hip_bf16.h>

#define NN 50000
#define PADN 50048            // 782*64 — padded row count
#define EE 800000
#define HH 256
#define EPSBN 1e-5f
#define NBLK ((NN + 255) / 256)   // 196 scan blocks
#define CR_BLK 391                // count_rank blocks (8 edges/thread)
#define CR_T (CR_BLK * 256)
#define FC_T 200192               // fill_csr threads (782 blocks * 256), 4 edges each
#define CVT_BLK 3128              // cvt blocks (PADN*128/8/256)

typedef unsigned int uint32;
typedef __attribute__((ext_vector_type(8))) short short8;   // 8 bf16 = 4 VGPR
typedef __attribute__((ext_vector_type(4))) float f32x4;
typedef __attribute__((ext_vector_type(2))) float f32x2;

__device__ __forceinline__ float bf2f(unsigned short u) {
    union { uint32 u; float f; } c; c.u = ((uint32)u) << 16; return c.f;
}
__device__ __forceinline__ unsigned short f2bf(float f) {
    __hip_bfloat16 h = __float2bfloat16(f);   // RNE
    return *reinterpret_cast<unsigned short*>(&h);
}
// pack 4 floats -> 4 fp8 e4m3 (OCP on gfx950), RNE+sat
__device__ __forceinline__ uint32 pkfp8(float a, float b, float c, float d) {
    int r = 0;
    r = __builtin_amdgcn_cvt_pk_fp8_f32(a, b, r, false);   // bytes 0,1
    r = __builtin_amdgcn_cvt_pk_fp8_f32(c, d, r, true);    // bytes 2,3
    return (uint32)r;
}

// ---------------- prologue ----------------

// fused: blocks [0,CR_BLK) run batched count_rank atomics (latency-bound);
// blocks [CR_BLK, CR_BLK+CVT_BLK) stream the fp32->bf16/fp8 conversion.
// The conversion's streaming work hides the atomic contention floor.
__global__ void cvt_count(const float* __restrict__ x, unsigned short* __restrict__ xb,
                          unsigned char* __restrict__ x8,
                          const int* __restrict__ dst, int* __restrict__ deg,
                          int* __restrict__ rank) {
    const int bid = (int)blockIdx.x;
    if (bid < CR_BLK) {
        // ---- count_rank role: 8 edges/thread, batch-issued atomics ----
        const int t = bid * 256 + (int)threadIdx.x;
        int d[8], r[8];
        #pragma unroll
        for (int k = 0; k < 8; ++k) {
            const int e = t + k * CR_T;
            d[k] = (e < EE) ? dst[e] : -1;
        }
        #pragma unroll
        for (int k = 0; k < 8; ++k)
            if (d[k] >= 0) r[k] = atomicAdd(&deg[d[k]], 1);
        #pragma unroll
        for (int k = 0; k < 8; ++k) {
            const int e = t + k * CR_T;
            if (d[k] >= 0) rank[e] = r[k];
        }
        return;
    }
    // ---- cvt role: 8 elems/thread, bf16 + fp8 copies of x ----
    const int i = (bid - CR_BLK) * 256 + (int)threadIdx.x;
    if (i >= PADN * 128 / 8) return;
    const int e0 = i * 8;
    float f[8];
    if (e0 + 8 <= NN * 128) {
        float4 u0 = *(const float4*)(x + e0);
        float4 u1 = *(const float4*)(x + e0 + 4);
        f[0] = u0.x; f[1] = u0.y; f[2] = u0.z; f[3] = u0.w;
        f[4] = u1.x; f[5] = u1.y; f[6] = u1.z; f[7] = u1.w;
    } else {
        #pragma unroll
        for (int k = 0; k < 8; ++k) f[k] = 0.f;   // pad rows
    }
    uint4 b;
    b.x = (uint32)f2bf(f[0]) | ((uint32)f2bf(f[1]) << 16);
    b.y = (uint32)f2bf(f[2]) | ((uint32)f2bf(f[3]) << 16);
    b.z = (uint32)f2bf(f[4]) | ((uint32)f2bf(f[5]) << 16);
    b.w = (uint32)f2bf(f[6]) | ((uint32)f2bf(f[7]) << 16);
    *(uint4*)(xb + e0) = b;
    uint2 p;
    p.x = pkfp8(f[0], f[1], f[2], f[3]);
    p.y = pkfp8(f[4], f[5], f[6], f[7]);
    *(uint2*)(x8 + e0) = p;
}

// Wpack layout (bf16 elems): idx = ((s*16 + nf)*512 + l*8 + e)
__device__ __forceinline__ void pack_one(const float* __restrict__ Wl,
                                         const float* __restrict__ Wr,
                                         unsigned short* __restrict__ Wp,
                                         int C, int idx) {
    int e  = idx & 7;
    int ll = (idx >> 3) & 63;
    int nf = (idx >> 9) & 15;
    int s  = idx >> 13;
    int KSl = C / 32;
    const float* W = (s < KSl) ? Wl : Wr;
    int ks = (s < KSl) ? s : s - KSl;
    int k = ks * 32 + (ll >> 4) * 8 + e;
    int n = nf * 16 + (ll & 15);
    Wp[idx] = f2bf(W[(size_t)k * HH + n]);
}

// fused: blocks [0,NBLK) per-block deg reduce; blocks [NBLK,...) pack weights
__global__ void scan_pack(const int* __restrict__ deg, int* __restrict__ bsum,
                          const float* __restrict__ Wl0, const float* __restrict__ Wr0,
                          unsigned short* __restrict__ Wp0,
                          const float* __restrict__ Wl1, const float* __restrict__ Wr1,
                          unsigned short* __restrict__ Wp1,
                          const float* __restrict__ Wl2, const float* __restrict__ Wr2,
                          unsigned short* __restrict__ Wp2) {
    const int bid = (int)blockIdx.x;
    if (bid < NBLK) {
        __shared__ int sd[256];
        const int t = (int)threadIdx.x;
        const int i = bid * 256 + t;
        sd[t] = (i < NN) ? deg[i] : 0;
        __syncthreads();
        #pragma unroll
        for (int off = 128; off > 0; off >>= 1) {
            if (t < off) sd[t] += sd[t + off];
            __syncthreads();
        }
        if (t == 0) bsum[bid] = sd[0];
        return;
    }
    const int idx = (bid - NBLK) * 256 + (int)threadIdx.x;
    if (idx < 65536)       pack_one(Wl0, Wr0, Wp0, 128, idx);
    else if (idx < 196608) pack_one(Wl1, Wr1, Wp1, 256, idx - 65536);
    else if (idx < 327680) pack_one(Wl2, Wr2, Wp2, 256, idx - 196608);
}

// merged: each block re-reduces bsum[0..b-1] for its offset, then scans its chunk
__global__ void scan_fin(const int* __restrict__ deg, const int* __restrict__ bsum,
                         int* __restrict__ rowstart) {
    __shared__ int sb[256];
    __shared__ int sd[256];
    const int t = (int)threadIdx.x;
    const int b = (int)blockIdx.x;
    sb[t] = (t < NBLK && t < b) ? bsum[t] : 0;
    __syncthreads();
    #pragma unroll
    for (int off = 128; off > 0; off >>= 1) {
        if (t < off) sb[t] += sb[t + off];
        __syncthreads();
    }
    const int boff = sb[0];
    const int i = b * 256 + t;
    const int v = (i < NN) ? deg[i] : 0;
    sd[t] = v;
    __syncthreads();
    #pragma unroll
    for (int off = 1; off < 256; off <<= 1) {
        int u = (t >= off) ? sd[t - off] : 0;
        __syncthreads();
        sd[t] += u;
        __syncthreads();
    }
    if (i < NN) rowstart[i] = boff + sd[t] - v;
    if (i == 0) rowstart[NN] = EE;
}

// 4 edges/thread, batched dependent gather + scattered store
__global__ void fill_csr2(const int* __restrict__ src, const int* __restrict__ dst,
                          const int* __restrict__ rank, const int* __restrict__ rowstart,
                          int* __restrict__ col) {
    const int t = (int)(blockIdx.x * blockDim.x + threadIdx.x);
    int d[4], r[4], s[4], p[4];
    #pragma unroll
    for (int k = 0; k < 4; ++k) {
        const int e = t + k * FC_T;
        const bool ok = e < EE;
        d[k] = ok ? dst[e] : -1;
        r[k] = ok ? rank[e] : 0;
        s[k] = ok ? src[e] : 0;
    }
    #pragma unroll
    for (int k = 0; k < 4; ++k)
        if (d[k] >= 0) p[k] = rowstart[d[k]];
    #pragma unroll
    for (int k = 0; k < 4; ++k)
        if (d[k] >= 0) col[p[k] + r[k]] = s[k];
}

// ---------------- mean aggregation (fp8 gather -> bf16 out), one wave/node ----------------
// R9 config (best measured): 8B/lane gathers, 4 rows in flight, 28 VGPR, no LDS
// -> ~21 waves/CU. Rows-in-flight/CU ≈ waves x 4 beats per-lane depth (R10 lesson).

__device__ __forceinline__ void acc8f(float* a, uint2 v) {
    f32x2 f0 = __builtin_amdgcn_cvt_pk_f32_fp8(v.x, false);
    f32x2 f1 = __builtin_amdgcn_cvt_pk_f32_fp8(v.x, true);
    f32x2 f2 = __builtin_amdgcn_cvt_pk_f32_fp8(v.y, false);
    f32x2 f3 = __builtin_amdgcn_cvt_pk_f32_fp8(v.y, true);
    a[0] += f0.x; a[1] += f0.y; a[2] += f1.x; a[3] += f1.y;
    a[4] += f2.x; a[5] += f2.y; a[6] += f3.x; a[7] += f3.y;
}

template<int C>
__global__ void agg_mean_8(const unsigned char* __restrict__ h8, const int* __restrict__ rowstart,
                           const int* __restrict__ col,
                           unsigned short* __restrict__ agg) {
    const int wid = (int)((blockIdx.x * blockDim.x + threadIdx.x) >> 6);
    const int l   = (int)(threadIdx.x & 63);
    if (wid >= NN) return;
    const int beg = rowstart[wid], end = rowstart[wid + 1];
    const int d   = end - beg;
    const float inv = 1.0f / (float)(d > 1 ? d : 1);
    float a[8] = {0.f, 0.f, 0.f, 0.f, 0.f, 0.f, 0.f, 0.f};

    if (C == 256) {
        const int half = l >> 5;
        const int cl   = l & 31;
        const unsigned char* base = h8 + cl * 8;
        int j = beg + half;
        for (; j + 6 < end; j += 8) {
            int c0 = col[j], c1 = col[j + 2], c2 = col[j + 4], c3 = col[j + 6];
            uint2 v0 = *(const uint2*)(base + (size_t)c0 * C);
            uint2 v1 = *(const uint2*)(base + (size_t)c1 * C);
            uint2 v2 = *(const uint2*)(base + (size_t)c2 * C);
            uint2 v3 = *(const uint2*)(base + (size_t)c3 * C);
            acc8f(a, v0); acc8f(a, v1); acc8f(a, v2); acc8f(a, v3);
        }
        for (; j < end; j += 2) {
            uint2 v0 = *(const uint2*)(base + (size_t)col[j] * C);
            acc8f(a, v0);
        }
        #pragma unroll
        for (int k = 0; k < 8; ++k) a[k] += __shfl_xor(a[k], 32, 64);
        if (half == 0) {
            uint4 o;
            o.x = (uint32)f2bf(a[0] * inv) | ((uint32)f2bf(a[1] * inv) << 16);
            o.y = (uint32)f2bf(a[2] * inv) | ((uint32)f2bf(a[3] * inv) << 16);
            o.z = (uint32)f2bf(a[4] * inv) | ((uint32)f2bf(a[5] * inv) << 16);
            o.w = (uint32)f2bf(a[6] * inv) | ((uint32)f2bf(a[7] * inv) << 16);
            *(uint4*)(agg + (size_t)wid * C + cl * 8) = o;
        }
    } else {  // C == 128
        const int q  = l >> 4;
        const int cl = l & 15;
        const unsigned char* base = h8 + cl * 8;
        int j = beg + q;
        for (; j + 12 < end; j += 16) {
            int c0 = col[j], c1 = col[j + 4], c2 = col[j + 8], c3 = col[j + 12];
            uint2 v0 = *(const uint2*)(base + (size_t)c0 * C);
            uint2 v1 = *(const uint2*)(base + (size_t)c1 * C);
            uint2 v2 = *(const uint2*)(base + (size_t)c2 * C);
            uint2 v3 = *(const uint2*)(base + (size_t)c3 * C);
            acc8f(a, v0); acc8f(a, v1); acc8f(a, v2); acc8f(a, v3);
        }
        for (; j < end; j += 4) {
            uint2 v0 = *(const uint2*)(base + (size_t)col[j] * C);
            acc8f(a, v0);
        }
        #pragma unroll
        for (int k = 0; k < 8; ++k) {
            a[k] += __shfl_xor(a[k], 16, 64);
            a[k] += __shfl_xor(a[k], 32, 64);
        }
        if (q == 0) {
            uint4 o;
            o.x = (uint32)f2bf(a[0] * inv) | ((uint32)f2bf(a[1] * inv) << 16);
            o.y = (uint32)f2bf(a[2] * inv) | ((uint32)f2bf(a[3] * inv) << 16);
            o.z = (uint32)f2bf(a[4] * inv) | ((uint32)f2bf(a[5] * inv) << 16);
            o.w = (uint32)f2bf(a[6] * inv) | ((uint32)f2bf(a[7] * inv) << 16);
            *(uint4*)(agg + (size_t)wid * C + cl * 8) = o;
        }
    }
}

// ---------------- MFMA GEMM: out = relu(BN(agg@Wl + h@Wr + b)) ----------------
// 64 rows x 256 cols per block, 4 waves, K = 2*C fused, BK=64 staging.
// Output staged through LDS for fully-coalesced stores.

#define CPAD 260   // padded cols (f32 rows: stride 1040B; bf16 rows: 520B)

template<int C, bool FINAL>
__global__ __launch_bounds__(256)
void gemm_mfma(const unsigned short* __restrict__ Aagg, const unsigned short* __restrict__ Ain,
               const unsigned short* __restrict__ Wpack,
               const float* __restrict__ bias, const float* __restrict__ gamma,
               const float* __restrict__ beta, const float* __restrict__ rmean,
               const float* __restrict__ rvar,
               float* __restrict__ outf, unsigned short* __restrict__ outb,
               unsigned char* __restrict__ out8)
{
    constexpr int KS = C / 32;      // k-steps per matrix
    constexpr int S  = 2 * KS;      // total k-steps (agg@Wl then h@Wr)
    constexpr int NS = S / 2;       // stages (2 k-steps each)
    __shared__ unsigned short Alds[2][4][1024];      // dbuf x m-frag x (2 ksteps * 512)
    __shared__ __align__(16) unsigned char Cbuf[33280];  // f32 32xCPAD | bf16 64xCPAD
    const int tid = (int)threadIdx.x;
    const int wid = tid >> 6;       // wave -> 64-col slab
    const int l   = tid & 63;
    const int row0 = (int)blockIdx.x * 64;

    const int srow  = row0 + wid * 16 + (l & 15);
    const int skoff = (l >> 4) * 8;

    f32x4 acc[4][4];
    #pragma unroll
    for (int m = 0; m < 4; ++m)
        #pragma unroll
        for (int n = 0; n < 4; ++n)
            acc[m][n] = (f32x4){0.f, 0.f, 0.f, 0.f};

    auto stage = [&](int buf, int st) {
        #pragma unroll
        for (int k2 = 0; k2 < 2; ++k2) {
            const int s = st * 2 + k2;
            const unsigned short* Asrc = (s < KS) ? Aagg : Ain;
            const int ks = (s < KS) ? s : s - KS;
            const unsigned short* gp = Asrc + (size_t)srow * C + ks * 32 + skoff;
            __builtin_amdgcn_global_load_lds(
                (const __attribute__((address_space(1))) uint32*)gp,
                (__attribute__((address_space(3))) uint32*)(&Alds[buf][wid][k2 * 512]),
                16, 0, 0);
        }
    };

    stage(0, 0);
    int cur = 0;
    for (int st = 0; st < NS; ++st) {
        __syncthreads();                        // Alds[cur] staged (vmcnt drained)
        if (st + 1 < NS) stage(cur ^ 1, st + 1);
        short8 b[2][4];
        #pragma unroll
        for (int k2 = 0; k2 < 2; ++k2)
            #pragma unroll
            for (int n = 0; n < 4; ++n) {
                size_t off = ((size_t)(st * 2 + k2) * 16 + wid * 4 + n) * 512 + l * 8;
                b[k2][n] = *(const short8*)(Wpack + off);
            }
        short8 a[2][4];
        #pragma unroll
        for (int k2 = 0; k2 < 2; ++k2)
            #pragma unroll
            for (int m = 0; m < 4; ++m)
                a[k2][m] = *(const short8*)(&Alds[cur][m][k2 * 512 + l * 8]);
        #pragma unroll
        for (int k2 = 0; k2 < 2; ++k2)
            #pragma unroll
            for (int m = 0; m < 4; ++m)
                #pragma unroll
                for (int n = 0; n < 4; ++n)
                    acc[m][n] = __builtin_amdgcn_mfma_f32_16x16x32_bf16(a[k2][m], b[k2][n], acc[m][n], 0, 0, 0);
        cur ^= 1;
    }

    // BN constants per output column (4 n-frags)
    float sj[4], cj[4];
    #pragma unroll
    for (int n = 0; n < 4; ++n) {
        const int jj = wid * 64 + n * 16 + (l & 15);
        sj[n] = gamma[jj] * rsqrtf(rvar[jj] + EPSBN);
        cj[n] = (bias[jj] - rmean[jj]) * sj[n] + beta[jj];
    }

    if (FINAL) {
        // two half-passes: rows 0-31 (m=0,1) then 32-63 (m=2,3), f32 through LDS
        float* Cf = (float*)Cbuf;
        #pragma unroll
        for (int half = 0; half < 2; ++half) {
            if (half) __syncthreads();          // protect Cf reuse
            #pragma unroll
            for (int n = 0; n < 4; ++n) {
                const int jj = wid * 64 + n * 16 + (l & 15);
                #pragma unroll
                for (int mm = 0; mm < 2; ++mm) {
                    const int m  = half * 2 + mm;
                    const int rb = mm * 16 + (l >> 4) * 4;   // 0..31 within half
                    #pragma unroll
                    for (int j = 0; j < 4; ++j) {
                        float v = acc[m][n][j] * sj[n] + cj[n];
                        Cf[(rb + j) * CPAD + jj] = v > 0.f ? v : 0.f;
                    }
                }
            }
            __syncthreads();
            const int col4 = (tid & 63) * 4;
            const int rw   = tid >> 6;
            #pragma unroll
            for (int i = 0; i < 8; ++i) {
                const int row  = i * 4 + rw;
                const int grow = row0 + half * 32 + row;
                if (grow < NN) {
                    float4 v = *(const float4*)&Cf[row * CPAD + col4];
                    *(float4*)(outf + (size_t)grow * HH + col4) = v;
                }
            }
        }
    } else {
        unsigned short* Clds = (unsigned short*)Cbuf;
        #pragma unroll
        for (int n = 0; n < 4; ++n) {
            const int jj = wid * 64 + n * 16 + (l & 15);
            #pragma unroll
            for (int m = 0; m < 4; ++m) {
                const int rb = m * 16 + (l >> 4) * 4;
                #pragma unroll
                for (int j = 0; j < 4; ++j) {
                    float v = acc[m][n][j] * sj[n] + cj[n];
                    Clds[(rb + j) * CPAD + jj] = f2bf(v > 0.f ? v : 0.f);
                }
            }
        }
        __syncthreads();
        // linear write-out: bf16 (16B/thread x8) + fp8 gather copy (8B/thread x8)
        #pragma unroll
        for (int i = 0; i < 8; ++i) {
            const int row  = i * 8 + (tid >> 5);
            const int col8 = (tid & 31) * 8;
            uint4 v = *(const uint4*)&Clds[row * CPAD + col8];
            *(uint4*)(outb + ((size_t)(row0 + row)) * HH + col8) = v;
            uint2 p;
            p.x = pkfp8(bf2f((unsigned short)(v.x & 0xffff)), bf2f((unsigned short)(v.x >> 16)),
                        bf2f((unsigned short)(v.y & 0xffff)), bf2f((unsigned short)(v.y >> 16)));
            p.y = pkfp8(bf2f((unsigned short)(v.z & 0xffff)), bf2f((unsigned short)(v.z >> 16)),
                        bf2f((unsigned short)(v.w & 0xffff)), bf2f((unsigned short)(v.w >> 16)));
            *(uint2*)(out8 + ((size_t)(row0 + row)) * HH + col8) = p;
        }
    }
}

// ---------------- launch ----------------

static inline size_t alignup(size_t x) { return (x + 511) & ~(size_t)511; }

extern "C" void kernel_launch(void* const* d_in, const int* in_sizes, int n_in,
                              void* d_out, int out_size, void* d_ws, size_t ws_size,
                              hipStream_t stream) {
    const float* x   = (const float*)d_in[0];
    const int*   ei  = (const int*)d_in[1];
    const int*   src = ei;
    const int*   dst = ei + EE;
    const float* gamma = (const float*)d_in[2];
    const float* beta  = (const float*)d_in[3];
    const float* rmean = (const float*)d_in[4];
    const float* rvar  = (const float*)d_in[5];
    const float* Wl0 = (const float*)d_in[6];
    const float* Wr0 = (const float*)d_in[7];
    const float* b0  = (const float*)d_in[8];
    const float* Wl1 = (const float*)d_in[9];
    const float* Wr1 = (const float*)d_in[10];
    const float* b1  = (const float*)d_in[11];
    const float* Wl2 = (const float*)d_in[12];
    const float* Wr2 = (const float*)d_in[13];
    const float* b2  = (const float*)d_in[14];
    float* out = (float*)d_out;
    (void)ws_size; (void)n_in; (void)in_sizes; (void)out_size;

    char* w = (char*)d_ws;
    size_t off = 0;
    int*   deg      = (int*)(w + off);   off += alignup(NN * 4);
    int*   rank     = (int*)(w + off);   off += alignup((size_t)EE * 4);
    int*   rowstart = (int*)(w + off);   off += alignup((NN + 1) * 4);
    int*   bsum     = (int*)(w + off);   off += alignup(NBLK * 4);
    int*   col      = (int*)(w + off);   off += alignup((size_t)EE * 4);
    unsigned short* xb   = (unsigned short*)(w + off); off += alignup((size_t)PADN * 128 * 2);
    unsigned short* agg  = (unsigned short*)(w + off); off += alignup((size_t)PADN * HH * 2);
    unsigned short* h1   = (unsigned short*)(w + off); off += alignup((size_t)PADN * HH * 2);
    unsigned short* h2   = (unsigned short*)(w + off); off += alignup((size_t)PADN * HH * 2);
    unsigned char*  x8   = (unsigned char*)(w + off);  off += alignup((size_t)PADN * 128);
    unsigned char*  h1_8 = (unsigned char*)(w + off);  off += alignup((size_t)PADN * HH);
    unsigned char*  h2_8 = (unsigned char*)(w + off);  off += alignup((size_t)PADN * HH);
    unsigned short* Wp0  = (unsigned short*)(w + off); off += alignup((size_t)2 * 128 * 256 * 2);
    unsigned short* Wp1  = (unsigned short*)(w + off); off += alignup((size_t)2 * 256 * 256 * 2);
    unsigned short* Wp2  = (unsigned short*)(w + off); off += alignup((size_t)2 * 256 * 256 * 2);

    // prologue (5 dispatches + memset): deg-zero, fused cvt+count, fused scan+pack,
    // scan_fin, fill
    hipMemsetAsync(deg, 0, NN * 4, stream);
    cvt_count<<<CR_BLK + CVT_BLK, 256, 0, stream>>>(x, xb, x8, dst, deg, rank);
    scan_pack<<<NBLK + 1280, 256, 0, stream>>>(deg, bsum,
        Wl0, Wr0, Wp0, Wl1, Wr1, Wp1, Wl2, Wr2, Wp2);
    scan_fin <<<NBLK, 256, 0, stream>>>(deg, bsum, rowstart);
    fill_csr2<<<FC_T / 256, 256, 0, stream>>>(src, dst, rank, rowstart, col);

    const int agg_grid  = (NN * 64 + 255) / 256;
    const int gemm_grid = PADN / 64;   // 782

    // layer 0 (C=128)
    agg_mean_8<128><<<agg_grid, 256, 0, stream>>>(x8, rowstart, col, agg);
    gemm_mfma<128, false><<<gemm_grid, 256, 0, stream>>>(agg, xb, Wp0,
        b0, gamma + 0 * HH, beta + 0 * HH, rmean + 0 * HH, rvar + 0 * HH, nullptr, h1, h1_8);

    // layer 1 (C=256)
    agg_mean_8<256><<<agg_grid, 256, 0, stream>>>(h1_8, rowstart, col, agg);
    gemm_mfma<256, false><<<gemm_grid, 256, 0, stream>>>(agg, h1, Wp1,
        b1, gamma + 1 * HH, beta + 1 * HH, rmean + 1 * HH, rvar + 1 * HH, nullptr, h2, h2_8);

    // layer 2 (C=256)
    agg_mean_8<256><<<agg_grid, 256, 0, stream>>>(h2_8, rowstart, col, agg);
    gemm_mfma<256, true><<<gemm_grid, 256, 0, stream>>>(agg, h2, Wp2,
        b2, gamma + 2 * HH, beta + 2 * HH, rmean + 2 * HH, rvar + 2 * HH, out, nullptr, nullptr);
}

// Round 13
// 324.777 us; speedup vs baseline: 1.1015x; 1.0166x over previous
//
#include <hip/hip_runtime.h>
#include <hip/hip_bf16.h>

#define NN 50000
#define PADN 50048            // 782*64 — padded row count
#define EE 800000
#define HH 256
#define EPSBN 1e-5f
#define NBLK ((NN + 255) / 256)   // 196 scan blocks
#define CR_BLK 391                // count_rank blocks (8 edges/thread)
#define CR_T (CR_BLK * 256)
#define FC_T 200192               // fill_csr threads (782 blocks * 256), 4 edges each
#define CVT_BLK 3128              // cvt blocks (PADN*128/8/256)

typedef unsigned int uint32;
typedef __attribute__((ext_vector_type(8))) short short8;   // 8 bf16 = 4 VGPR
typedef __attribute__((ext_vector_type(4))) float f32x4;
typedef __attribute__((ext_vector_type(2))) float f32x2;

__device__ __forceinline__ float bf2f(unsigned short u) {
    union { uint32 u; float f; } c; c.u = ((uint32)u) << 16; return c.f;
}
__device__ __forceinline__ unsigned short f2bf(float f) {
    __hip_bfloat16 h = __float2bfloat16(f);   // RNE
    return *reinterpret_cast<unsigned short*>(&h);
}
// pack 4 floats -> 4 fp8 e4m3 (OCP on gfx950), RNE+sat
__device__ __forceinline__ uint32 pkfp8(float a, float b, float c, float d) {
    int r = 0;
    r = __builtin_amdgcn_cvt_pk_fp8_f32(a, b, r, false);   // bytes 0,1
    r = __builtin_amdgcn_cvt_pk_fp8_f32(c, d, r, true);    // bytes 2,3
    return (uint32)r;
}

// ---------------- prologue ----------------

// fused: blocks [0,CR_BLK) run batched count_rank atomics (latency-bound);
// blocks [CR_BLK, CR_BLK+CVT_BLK) stream the fp32->bf16/fp8 conversion.
__global__ void cvt_count(const float* __restrict__ x, unsigned short* __restrict__ xb,
                          unsigned char* __restrict__ x8,
                          const int* __restrict__ dst, int* __restrict__ deg,
                          int* __restrict__ rank) {
    const int bid = (int)blockIdx.x;
    if (bid < CR_BLK) {
        const int t = bid * 256 + (int)threadIdx.x;
        int d[8], r[8];
        #pragma unroll
        for (int k = 0; k < 8; ++k) {
            const int e = t + k * CR_T;
            d[k] = (e < EE) ? dst[e] : -1;
        }
        #pragma unroll
        for (int k = 0; k < 8; ++k)
            if (d[k] >= 0) r[k] = atomicAdd(&deg[d[k]], 1);
        #pragma unroll
        for (int k = 0; k < 8; ++k) {
            const int e = t + k * CR_T;
            if (d[k] >= 0) rank[e] = r[k];
        }
        return;
    }
    const int i = (bid - CR_BLK) * 256 + (int)threadIdx.x;
    if (i >= PADN * 128 / 8) return;
    const int e0 = i * 8;
    float f[8];
    if (e0 + 8 <= NN * 128) {
        float4 u0 = *(const float4*)(x + e0);
        float4 u1 = *(const float4*)(x + e0 + 4);
        f[0] = u0.x; f[1] = u0.y; f[2] = u0.z; f[3] = u0.w;
        f[4] = u1.x; f[5] = u1.y; f[6] = u1.z; f[7] = u1.w;
    } else {
        #pragma unroll
        for (int k = 0; k < 8; ++k) f[k] = 0.f;   // pad rows
    }
    uint4 b;
    b.x = (uint32)f2bf(f[0]) | ((uint32)f2bf(f[1]) << 16);
    b.y = (uint32)f2bf(f[2]) | ((uint32)f2bf(f[3]) << 16);
    b.z = (uint32)f2bf(f[4]) | ((uint32)f2bf(f[5]) << 16);
    b.w = (uint32)f2bf(f[6]) | ((uint32)f2bf(f[7]) << 16);
    *(uint4*)(xb + e0) = b;
    uint2 p;
    p.x = pkfp8(f[0], f[1], f[2], f[3]);
    p.y = pkfp8(f[4], f[5], f[6], f[7]);
    *(uint2*)(x8 + e0) = p;
}

// Wpack layout (bf16 elems): idx = ((s*16 + nf)*512 + l*8 + e)
__device__ __forceinline__ void pack_one(const float* __restrict__ Wl,
                                         const float* __restrict__ Wr,
                                         unsigned short* __restrict__ Wp,
                                         int C, int idx) {
    int e  = idx & 7;
    int ll = (idx >> 3) & 63;
    int nf = (idx >> 9) & 15;
    int s  = idx >> 13;
    int KSl = C / 32;
    const float* W = (s < KSl) ? Wl : Wr;
    int ks = (s < KSl) ? s : s - KSl;
    int k = ks * 32 + (ll >> 4) * 8 + e;
    int n = nf * 16 + (ll & 15);
    Wp[idx] = f2bf(W[(size_t)k * HH + n]);
}

// fused: blocks [0,NBLK) per-block deg reduce; blocks [NBLK,...) pack weights
__global__ void scan_pack(const int* __restrict__ deg, int* __restrict__ bsum,
                          const float* __restrict__ Wl0, const float* __restrict__ Wr0,
                          unsigned short* __restrict__ Wp0,
                          const float* __restrict__ Wl1, const float* __restrict__ Wr1,
                          unsigned short* __restrict__ Wp1,
                          const float* __restrict__ Wl2, const float* __restrict__ Wr2,
                          unsigned short* __restrict__ Wp2) {
    const int bid = (int)blockIdx.x;
    if (bid < NBLK) {
        __shared__ int sd[256];
        const int t = (int)threadIdx.x;
        const int i = bid * 256 + t;
        sd[t] = (i < NN) ? deg[i] : 0;
        __syncthreads();
        #pragma unroll
        for (int off = 128; off > 0; off >>= 1) {
            if (t < off) sd[t] += sd[t + off];
            __syncthreads();
        }
        if (t == 0) bsum[bid] = sd[0];
        return;
    }
    const int idx = (bid - NBLK) * 256 + (int)threadIdx.x;
    if (idx < 65536)       pack_one(Wl0, Wr0, Wp0, 128, idx);
    else if (idx < 196608) pack_one(Wl1, Wr1, Wp1, 256, idx - 65536);
    else if (idx < 327680) pack_one(Wl2, Wr2, Wp2, 256, idx - 196608);
}

// merged: each block re-reduces bsum[0..b-1] for its offset, then scans its chunk
__global__ void scan_fin(const int* __restrict__ deg, const int* __restrict__ bsum,
                         int* __restrict__ rowstart) {
    __shared__ int sb[256];
    __shared__ int sd[256];
    const int t = (int)threadIdx.x;
    const int b = (int)blockIdx.x;
    sb[t] = (t < NBLK && t < b) ? bsum[t] : 0;
    __syncthreads();
    #pragma unroll
    for (int off = 128; off > 0; off >>= 1) {
        if (t < off) sb[t] += sb[t + off];
        __syncthreads();
    }
    const int boff = sb[0];
    const int i = b * 256 + t;
    const int v = (i < NN) ? deg[i] : 0;
    sd[t] = v;
    __syncthreads();
    #pragma unroll
    for (int off = 1; off < 256; off <<= 1) {
        int u = (t >= off) ? sd[t - off] : 0;
        __syncthreads();
        sd[t] += u;
        __syncthreads();
    }
    if (i < NN) rowstart[i] = boff + sd[t] - v;
    if (i == 0) rowstart[NN] = EE;
}

// 4 edges/thread, batched dependent gather + scattered store
__global__ void fill_csr2(const int* __restrict__ src, const int* __restrict__ dst,
                          const int* __restrict__ rank, const int* __restrict__ rowstart,
                          int* __restrict__ col) {
    const int t = (int)(blockIdx.x * blockDim.x + threadIdx.x);
    int d[4], r[4], s[4], p[4];
    #pragma unroll
    for (int k = 0; k < 4; ++k) {
        const int e = t + k * FC_T;
        const bool ok = e < EE;
        d[k] = ok ? dst[e] : -1;
        r[k] = ok ? rank[e] : 0;
        s[k] = ok ? src[e] : 0;
    }
    #pragma unroll
    for (int k = 0; k < 4; ++k)
        if (d[k] >= 0) p[k] = rowstart[d[k]];
    #pragma unroll
    for (int k = 0; k < 4; ++k)
        if (d[k] >= 0) col[p[k] + r[k]] = s[k];
}

// ---------------- mean aggregation (fp8 gather -> bf16 out), one wave/node ----------------
// R9 config (best measured): 8B/lane gathers, 4 rows in flight, 28 VGPR, no LDS.

__device__ __forceinline__ void acc8f(float* a, uint2 v) {
    f32x2 f0 = __builtin_amdgcn_cvt_pk_f32_fp8(v.x, false);
    f32x2 f1 = __builtin_amdgcn_cvt_pk_f32_fp8(v.x, true);
    f32x2 f2 = __builtin_amdgcn_cvt_pk_f32_fp8(v.y, false);
    f32x2 f3 = __builtin_amdgcn_cvt_pk_f32_fp8(v.y, true);
    a[0] += f0.x; a[1] += f0.y; a[2] += f1.x; a[3] += f1.y;
    a[4] += f2.x; a[5] += f2.y; a[6] += f3.x; a[7] += f3.y;
}

template<int C>
__global__ void agg_mean_8(const unsigned char* __restrict__ h8, const int* __restrict__ rowstart,
                           const int* __restrict__ col,
                           unsigned short* __restrict__ agg) {
    const int wid = (int)((blockIdx.x * blockDim.x + threadIdx.x) >> 6);
    const int l   = (int)(threadIdx.x & 63);
    if (wid >= NN) return;
    const int beg = rowstart[wid], end = rowstart[wid + 1];
    const int d   = end - beg;
    const float inv = 1.0f / (float)(d > 1 ? d : 1);
    float a[8] = {0.f, 0.f, 0.f, 0.f, 0.f, 0.f, 0.f, 0.f};

    if (C == 256) {
        const int half = l >> 5;
        const int cl   = l & 31;
        const unsigned char* base = h8 + cl * 8;
        int j = beg + half;
        for (; j + 6 < end; j += 8) {
            int c0 = col[j], c1 = col[j + 2], c2 = col[j + 4], c3 = col[j + 6];
            uint2 v0 = *(const uint2*)(base + (size_t)c0 * C);
            uint2 v1 = *(const uint2*)(base + (size_t)c1 * C);
            uint2 v2 = *(const uint2*)(base + (size_t)c2 * C);
            uint2 v3 = *(const uint2*)(base + (size_t)c3 * C);
            acc8f(a, v0); acc8f(a, v1); acc8f(a, v2); acc8f(a, v3);
        }
        for (; j < end; j += 2) {
            uint2 v0 = *(const uint2*)(base + (size_t)col[j] * C);
            acc8f(a, v0);
        }
        #pragma unroll
        for (int k = 0; k < 8; ++k) a[k] += __shfl_xor(a[k], 32, 64);
        if (half == 0) {
            uint4 o;
            o.x = (uint32)f2bf(a[0] * inv) | ((uint32)f2bf(a[1] * inv) << 16);
            o.y = (uint32)f2bf(a[2] * inv) | ((uint32)f2bf(a[3] * inv) << 16);
            o.z = (uint32)f2bf(a[4] * inv) | ((uint32)f2bf(a[5] * inv) << 16);
            o.w = (uint32)f2bf(a[6] * inv) | ((uint32)f2bf(a[7] * inv) << 16);
            *(uint4*)(agg + (size_t)wid * C + cl * 8) = o;
        }
    } else {  // C == 128
        const int q  = l >> 4;
        const int cl = l & 15;
        const unsigned char* base = h8 + cl * 8;
        int j = beg + q;
        for (; j + 12 < end; j += 16) {
            int c0 = col[j], c1 = col[j + 4], c2 = col[j + 8], c3 = col[j + 12];
            uint2 v0 = *(const uint2*)(base + (size_t)c0 * C);
            uint2 v1 = *(const uint2*)(base + (size_t)c1 * C);
            uint2 v2 = *(const uint2*)(base + (size_t)c2 * C);
            uint2 v3 = *(const uint2*)(base + (size_t)c3 * C);
            acc8f(a, v0); acc8f(a, v1); acc8f(a, v2); acc8f(a, v3);
        }
        for (; j < end; j += 4) {
            uint2 v0 = *(const uint2*)(base + (size_t)col[j] * C);
            acc8f(a, v0);
        }
        #pragma unroll
        for (int k = 0; k < 8; ++k) {
            a[k] += __shfl_xor(a[k], 16, 64);
            a[k] += __shfl_xor(a[k], 32, 64);
        }
        if (q == 0) {
            uint4 o;
            o.x = (uint32)f2bf(a[0] * inv) | ((uint32)f2bf(a[1] * inv) << 16);
            o.y = (uint32)f2bf(a[2] * inv) | ((uint32)f2bf(a[3] * inv) << 16);
            o.z = (uint32)f2bf(a[4] * inv) | ((uint32)f2bf(a[5] * inv) << 16);
            o.w = (uint32)f2bf(a[6] * inv) | ((uint32)f2bf(a[7] * inv) << 16);
            *(uint4*)(agg + (size_t)wid * C + cl * 8) = o;
        }
    }
}

// ---------------- MFMA GEMM: out = relu(BN(agg@Wl + h@Wr + b)) ----------------
// 64 rows x 256 cols per block, 4 waves, K = 2*C fused, BK=64 staging.
// LDS UNION: Alds (K-loop staging, 16KB) and Cbuf (epilogue, 33KB) are
// temporally disjoint -> one 33KB buffer. 49.6->33.3KB = 4 blocks/CU (was 3).

#define CPAD 260   // padded cols (f32 rows: stride 1040B; bf16 rows: 520B)

template<int C, bool FINAL>
__global__ __launch_bounds__(256)
void gemm_mfma(const unsigned short* __restrict__ Aagg, const unsigned short* __restrict__ Ain,
               const unsigned short* __restrict__ Wpack,
               const float* __restrict__ bias, const float* __restrict__ gamma,
               const float* __restrict__ beta, const float* __restrict__ rmean,
               const float* __restrict__ rvar,
               float* __restrict__ outf, unsigned short* __restrict__ outb,
               unsigned char* __restrict__ out8)
{
    constexpr int KS = C / 32;      // k-steps per matrix
    constexpr int S  = 2 * KS;      // total k-steps (agg@Wl then h@Wr)
    constexpr int NS = S / 2;       // stages (2 k-steps each)
    __shared__ __align__(16) unsigned char SMEM[33280];  // union: Alds | Cbuf
    // Alds view: [2][4][1024] ushort (16KB) during the K loop
    unsigned short (*Alds)[4][1024] = (unsigned short (*)[4][1024])SMEM;
    const int tid = (int)threadIdx.x;
    const int wid = tid >> 6;       // wave -> 64-col slab
    const int l   = tid & 63;
    const int row0 = (int)blockIdx.x * 64;

    const int srow  = row0 + wid * 16 + (l & 15);
    const int skoff = (l >> 4) * 8;

    f32x4 acc[4][4];
    #pragma unroll
    for (int m = 0; m < 4; ++m)
        #pragma unroll
        for (int n = 0; n < 4; ++n)
            acc[m][n] = (f32x4){0.f, 0.f, 0.f, 0.f};

    auto stage = [&](int buf, int st) {
        #pragma unroll
        for (int k2 = 0; k2 < 2; ++k2) {
            const int s = st * 2 + k2;
            const unsigned short* Asrc = (s < KS) ? Aagg : Ain;
            const int ks = (s < KS) ? s : s - KS;
            const unsigned short* gp = Asrc + (size_t)srow * C + ks * 32 + skoff;
            __builtin_amdgcn_global_load_lds(
                (const __attribute__((address_space(1))) uint32*)gp,
                (__attribute__((address_space(3))) uint32*)(&Alds[buf][wid][k2 * 512]),
                16, 0, 0);
        }
    };

    stage(0, 0);
    int cur = 0;
    for (int st = 0; st < NS; ++st) {
        __syncthreads();                        // Alds[cur] staged (vmcnt drained)
        if (st + 1 < NS) stage(cur ^ 1, st + 1);
        short8 b[2][4];
        #pragma unroll
        for (int k2 = 0; k2 < 2; ++k2)
            #pragma unroll
            for (int n = 0; n < 4; ++n) {
                size_t off = ((size_t)(st * 2 + k2) * 16 + wid * 4 + n) * 512 + l * 8;
                b[k2][n] = *(const short8*)(Wpack + off);
            }
        short8 a[2][4];
        #pragma unroll
        for (int k2 = 0; k2 < 2; ++k2)
            #pragma unroll
            for (int m = 0; m < 4; ++m)
                a[k2][m] = *(const short8*)(&Alds[cur][m][k2 * 512 + l * 8]);
        #pragma unroll
        for (int k2 = 0; k2 < 2; ++k2)
            #pragma unroll
            for (int m = 0; m < 4; ++m)
                #pragma unroll
                for (int n = 0; n < 4; ++n)
                    acc[m][n] = __builtin_amdgcn_mfma_f32_16x16x32_bf16(a[k2][m], b[k2][n], acc[m][n], 0, 0, 0);
        cur ^= 1;
    }
    __syncthreads();   // WAR: all waves done reading Alds before Cbuf overwrites it

    // BN constants per output column (4 n-frags)
    float sj[4], cj[4];
    #pragma unroll
    for (int n = 0; n < 4; ++n) {
        const int jj = wid * 64 + n * 16 + (l & 15);
        sj[n] = gamma[jj] * rsqrtf(rvar[jj] + EPSBN);
        cj[n] = (bias[jj] - rmean[jj]) * sj[n] + beta[jj];
    }

    if (FINAL) {
        // two half-passes: rows 0-31 (m=0,1) then 32-63 (m=2,3), f32 through LDS
        float* Cf = (float*)SMEM;
        #pragma unroll
        for (int half = 0; half < 2; ++half) {
            if (half) __syncthreads();          // protect Cf reuse between halves
            #pragma unroll
            for (int n = 0; n < 4; ++n) {
                const int jj = wid * 64 + n * 16 + (l & 15);
                #pragma unroll
                for (int mm = 0; mm < 2; ++mm) {
                    const int m  = half * 2 + mm;
                    const int rb = mm * 16 + (l >> 4) * 4;   // 0..31 within half
                    #pragma unroll
                    for (int j = 0; j < 4; ++j) {
                        float v = acc[m][n][j] * sj[n] + cj[n];
                        Cf[(rb + j) * CPAD + jj] = v > 0.f ? v : 0.f;
                    }
                }
            }
            __syncthreads();
            const int col4 = (tid & 63) * 4;
            const int rw   = tid >> 6;
            #pragma unroll
            for (int i = 0; i < 8; ++i) {
                const int row  = i * 4 + rw;
                const int grow = row0 + half * 32 + row;
                if (grow < NN) {
                    float4 v = *(const float4*)&Cf[row * CPAD + col4];
                    *(float4*)(outf + (size_t)grow * HH + col4) = v;
                }
            }
        }
    } else {
        unsigned short* Clds = (unsigned short*)SMEM;
        #pragma unroll
        for (int n = 0; n < 4; ++n) {
            const int jj = wid * 64 + n * 16 + (l & 15);
            #pragma unroll
            for (int m = 0; m < 4; ++m) {
                const int rb = m * 16 + (l >> 4) * 4;
                #pragma unroll
                for (int j = 0; j < 4; ++j) {
                    float v = acc[m][n][j] * sj[n] + cj[n];
                    Clds[(rb + j) * CPAD + jj] = f2bf(v > 0.f ? v : 0.f);
                }
            }
        }
        __syncthreads();
        // linear write-out: bf16 (16B/thread x8) + fp8 gather copy (8B/thread x8)
        #pragma unroll
        for (int i = 0; i < 8; ++i) {
            const int row  = i * 8 + (tid >> 5);
            const int col8 = (tid & 31) * 8;
            uint4 v = *(const uint4*)&Clds[row * CPAD + col8];
            *(uint4*)(outb + ((size_t)(row0 + row)) * HH + col8) = v;
            uint2 p;
            p.x = pkfp8(bf2f((unsigned short)(v.x & 0xffff)), bf2f((unsigned short)(v.x >> 16)),
                        bf2f((unsigned short)(v.y & 0xffff)), bf2f((unsigned short)(v.y >> 16)));
            p.y = pkfp8(bf2f((unsigned short)(v.z & 0xffff)), bf2f((unsigned short)(v.z >> 16)),
                        bf2f((unsigned short)(v.w & 0xffff)), bf2f((unsigned short)(v.w >> 16)));
            *(uint2*)(out8 + ((size_t)(row0 + row)) * HH + col8) = p;
        }
    }
}

// ---------------- launch ----------------

static inline size_t alignup(size_t x) { return (x + 511) & ~(size_t)511; }

extern "C" void kernel_launch(void* const* d_in, const int* in_sizes, int n_in,
                              void* d_out, int out_size, void* d_ws, size_t ws_size,
                              hipStream_t stream) {
    const float* x   = (const float*)d_in[0];
    const int*   ei  = (const int*)d_in[1];
    const int*   src = ei;
    const int*   dst = ei + EE;
    const float* gamma = (const float*)d_in[2];
    const float* beta  = (const float*)d_in[3];
    const float* rmean = (const float*)d_in[4];
    const float* rvar  = (const float*)d_in[5];
    const float* Wl0 = (const float*)d_in[6];
    const float* Wr0 = (const float*)d_in[7];
    const float* b0  = (const float*)d_in[8];
    const float* Wl1 = (const float*)d_in[9];
    const float* Wr1 = (const float*)d_in[10];
    const float* b1  = (const float*)d_in[11];
    const float* Wl2 = (const float*)d_in[12];
    const float* Wr2 = (const float*)d_in[13];
    const float* b2  = (const float*)d_in[14];
    float* out = (float*)d_out;
    (void)ws_size; (void)n_in; (void)in_sizes; (void)out_size;

    char* w = (char*)d_ws;
    size_t off = 0;
    int*   deg      = (int*)(w + off);   off += alignup(NN * 4);
    int*   rank     = (int*)(w + off);   off += alignup((size_t)EE * 4);
    int*   rowstart = (int*)(w + off);   off += alignup((NN + 1) * 4);
    int*   bsum     = (int*)(w + off);   off += alignup(NBLK * 4);
    int*   col      = (int*)(w + off);   off += alignup((size_t)EE * 4);
    unsigned short* xb   = (unsigned short*)(w + off); off += alignup((size_t)PADN * 128 * 2);
    unsigned short* agg  = (unsigned short*)(w + off); off += alignup((size_t)PADN * HH * 2);
    unsigned short* h1   = (unsigned short*)(w + off); off += alignup((size_t)PADN * HH * 2);
    unsigned short* h2   = (unsigned short*)(w + off); off += alignup((size_t)PADN * HH * 2);
    unsigned char*  x8   = (unsigned char*)(w + off);  off += alignup((size_t)PADN * 128);
    unsigned char*  h1_8 = (unsigned char*)(w + off);  off += alignup((size_t)PADN * HH);
    unsigned char*  h2_8 = (unsigned char*)(w + off);  off += alignup((size_t)PADN * HH);
    unsigned short* Wp0  = (unsigned short*)(w + off); off += alignup((size_t)2 * 128 * 256 * 2);
    unsigned short* Wp1  = (unsigned short*)(w + off); off += alignup((size_t)2 * 256 * 256 * 2);
    unsigned short* Wp2  = (unsigned short*)(w + off); off += alignup((size_t)2 * 256 * 256 * 2);

    // prologue: deg-zero memset, fused cvt+count, fused scan+pack, scan_fin, fill
    hipMemsetAsync(deg, 0, NN * 4, stream);
    cvt_count<<<CR_BLK + CVT_BLK, 256, 0, stream>>>(x, xb, x8, dst, deg, rank);
    scan_pack<<<NBLK + 1280, 256, 0, stream>>>(deg, bsum,
        Wl0, Wr0, Wp0, Wl1, Wr1, Wp1, Wl2, Wr2, Wp2);
    scan_fin <<<NBLK, 256, 0, stream>>>(deg, bsum, rowstart);
    fill_csr2<<<FC_T / 256, 256, 0, stream>>>(src, dst, rank, rowstart, col);

    const int agg_grid  = (NN * 64 + 255) / 256;
    const int gemm_grid = PADN / 64;   // 782

    // layer 0 (C=128)
    agg_mean_8<128><<<agg_grid, 256, 0, stream>>>(x8, rowstart, col, agg);
    gemm_mfma<128, false><<<gemm_grid, 256, 0, stream>>>(agg, xb, Wp0,
        b0, gamma + 0 * HH, beta + 0 * HH, rmean + 0 * HH, rvar + 0 * HH, nullptr, h1, h1_8);

    // layer 1 (C=256)
    agg_mean_8<256><<<agg_grid, 256, 0, stream>>>(h1_8, rowstart, col, agg);
    gemm_mfma<256, false><<<gemm_grid, 256, 0, stream>>>(agg, h1, Wp1,
        b1, gamma + 1 * HH, beta + 1 * HH, rmean + 1 * HH, rvar + 1 * HH, nullptr, h2, h2_8);

    // layer 2 (C=256)
    agg_mean_8<256><<<agg_grid, 256, 0, stream>>>(h2_8, rowstart, col, agg);
    gemm_mfma<256, true><<<gemm_grid, 256, 0, stream>>>(agg, h2, Wp2,
        b2, gamma + 2 * HH, beta + 2 * HH, rmean + 2 * HH, rvar + 2 * HH, out, nullptr, nullptr);
}